// Round 3
// baseline (783.699 us; speedup 1.0000x reference)
//
#include <hip/hip_runtime.h>

namespace {

constexpr int V   = 50257;
constexpr int H   = 1024;
constexpr int SEQ = 2048;

__device__ __forceinline__ float dot4(const float4 p, const float* __restrict__ x) {
  return p.x * x[0] + p.y * x[1] + p.z * x[2] + p.w * x[3];
}

__device__ __forceinline__ float wred(float v) {
#pragma unroll
  for (int off = 32; off; off >>= 1) v += __shfl_xor(v, off, 64);
  return v;
}

// ---------------- GRU layer 0: x = [emb[word]; last_context] (2048), h = last_hidden[0]
__global__ __launch_bounds__(256) void k_gru0(
    const int* __restrict__ word, const float* __restrict__ emb,
    const float* __restrict__ last_context, const float* __restrict__ last_hidden0,
    const float* __restrict__ W_ih, const float* __restrict__ W_hh,
    const float* __restrict__ b_ih, const float* __restrict__ b_hh,
    float* __restrict__ h_ws, float* __restrict__ h_out)
{
  __shared__ float xs[2 * H];
  __shared__ float hs[H];
  const int tid = threadIdx.x;
  const size_t wrow = (size_t)word[0] * H;
  for (int i = tid; i < H; i += 256) {
    xs[i]     = emb[wrow + i];
    xs[H + i] = last_context[i];
    hs[i]     = last_hidden0[i];
  }
  __syncthreads();
  const int wave = tid >> 6, lane = tid & 63;
  const int j = blockIdx.x * 4 + wave;   // gate row index, 0..1023
  float acc[6];
#pragma unroll
  for (int g = 0; g < 3; ++g) {
    const float4* Wr = (const float4*)(W_ih + (size_t)(g * H + j) * (2 * H));
    float a = 0.f;
#pragma unroll
    for (int c = 0; c < 8; ++c)
      a += dot4(Wr[c * 64 + lane], &xs[c * 256 + lane * 4]);
    acc[g] = a;
  }
#pragma unroll
  for (int g = 0; g < 3; ++g) {
    const float4* Wr = (const float4*)(W_hh + (size_t)(g * H + j) * H);
    float a = 0.f;
#pragma unroll
    for (int c = 0; c < 4; ++c)
      a += dot4(Wr[c * 64 + lane], &hs[c * 256 + lane * 4]);
    acc[3 + g] = a;
  }
#pragma unroll
  for (int g = 0; g < 6; ++g) acc[g] = wred(acc[g]);
  if (lane == 0) {
    float gir = acc[0] + b_ih[j];
    float giz = acc[1] + b_ih[H + j];
    float gin = acc[2] + b_ih[2 * H + j];
    float ghr = acc[3] + b_hh[j];
    float ghz = acc[4] + b_hh[H + j];
    float ghn = acc[5] + b_hh[2 * H + j];
    float r = 1.f / (1.f + expf(-(gir + ghr)));
    float z = 1.f / (1.f + expf(-(giz + ghz)));
    float n = tanhf(gin + r * ghn);
    float h = (1.f - z) * n + z * hs[j];
    h_ws[j]  = h;
    h_out[j] = h;
  }
}

// ---------------- GRU layer 1: x = h0 (fp32, 1024), h = last_hidden[1]
__global__ __launch_bounds__(256) void k_gru1(
    const float* __restrict__ x_ws, const float* __restrict__ last_hidden1,
    const float* __restrict__ W_ih, const float* __restrict__ W_hh,
    const float* __restrict__ b_ih, const float* __restrict__ b_hh,
    float* __restrict__ h_ws, float* __restrict__ h_out)
{
  __shared__ float xs[H];
  __shared__ float hs[H];
  const int tid = threadIdx.x;
  for (int i = tid; i < H; i += 256) {
    xs[i] = x_ws[i];
    hs[i] = last_hidden1[i];
  }
  __syncthreads();
  const int wave = tid >> 6, lane = tid & 63;
  const int j = blockIdx.x * 4 + wave;
  float acc[6];
#pragma unroll
  for (int g = 0; g < 3; ++g) {
    const float4* Wr = (const float4*)(W_ih + (size_t)(g * H + j) * H);
    float a = 0.f;
#pragma unroll
    for (int c = 0; c < 4; ++c)
      a += dot4(Wr[c * 64 + lane], &xs[c * 256 + lane * 4]);
    acc[g] = a;
  }
#pragma unroll
  for (int g = 0; g < 3; ++g) {
    const float4* Wr = (const float4*)(W_hh + (size_t)(g * H + j) * H);
    float a = 0.f;
#pragma unroll
    for (int c = 0; c < 4; ++c)
      a += dot4(Wr[c * 64 + lane], &hs[c * 256 + lane * 4]);
    acc[3 + g] = a;
  }
#pragma unroll
  for (int g = 0; g < 6; ++g) acc[g] = wred(acc[g]);
  if (lane == 0) {
    float gir = acc[0] + b_ih[j];
    float giz = acc[1] + b_ih[H + j];
    float gin = acc[2] + b_ih[2 * H + j];
    float ghr = acc[3] + b_hh[j];
    float ghz = acc[4] + b_hh[H + j];
    float ghn = acc[5] + b_hh[2 * H + j];
    float r = 1.f / (1.f + expf(-(gir + ghr)));
    float z = 1.f / (1.f + expf(-(giz + ghz)));
    float n = tanhf(gin + r * ghn);
    float h = (1.f - z) * n + z * hs[j];
    h_ws[j]  = h;
    h_out[j] = h;
  }
}

// ---------------- v = Wa^T @ h1   (ba dropped: softmax shift-invariant)
__global__ __launch_bounds__(256) void k_wat(
    const float* __restrict__ Wa, const float* __restrict__ h1, float* __restrict__ v)
{
  const int t = threadIdx.x, b = blockIdx.x;
  float a0 = 0.f, a1 = 0.f, a2 = 0.f, a3 = 0.f;
  for (int j = b * 16; j < b * 16 + 16; ++j) {
    float hj = h1[j];
    float4 w = ((const float4*)(Wa + (size_t)j * H))[t];
    a0 += hj * w.x;
    a1 += hj * w.y;
    a2 += hj * w.z;
    a3 += hj * w.w;
  }
  atomicAdd(&v[t * 4 + 0], a0);
  atomicAdd(&v[t * 4 + 1], a1);
  atomicAdd(&v[t * 4 + 2], a2);
  atomicAdd(&v[t * 4 + 3], a3);
}

// ---------------- scores[i] = enc[i] . v   (grid 512, wave per i)
__global__ __launch_bounds__(256) void k_scores(
    const float* __restrict__ enc, const float* __restrict__ v, float* __restrict__ sc)
{
  __shared__ float vs[H];
  const int tid = threadIdx.x;
  for (int i = tid; i < H; i += 256) vs[i] = v[i];
  __syncthreads();
  const int wave = tid >> 6, lane = tid & 63;
  const int i = blockIdx.x * 4 + wave;
  const float4* er = (const float4*)(enc + (size_t)i * H);
  float a = 0.f;
#pragma unroll
  for (int c = 0; c < 4; ++c)
    a += dot4(er[c * 64 + lane], &vs[c * 256 + lane * 4]);
  a = wred(a);
  if (lane == 0) sc[i] = a;
}

// ---------------- fused softmax + ctx (grid 128): each block redundantly
// reduces the 2048 scores (8 KB, L2-resident) then accumulates its i-slab.
// Block 0 additionally writes the normalized weights to out_att.
__global__ __launch_bounds__(256) void k_ctx(
    const float* __restrict__ enc, const float* __restrict__ sc,
    float* __restrict__ ctx, float* __restrict__ aw_out)
{
  __shared__ float red[256];
  const int tid = threadIdx.x, b = blockIdx.x;
  float m = -1e30f;
  for (int k = tid; k < SEQ; k += 256) m = fmaxf(m, sc[k]);
  red[tid] = m; __syncthreads();
  for (int s = 128; s; s >>= 1) { if (tid < s) red[tid] = fmaxf(red[tid], red[tid + s]); __syncthreads(); }
  const float M = red[0]; __syncthreads();
  float sum = 0.f;
  for (int k = tid; k < SEQ; k += 256) sum += expf(sc[k] - M);
  red[tid] = sum; __syncthreads();
  for (int s = 128; s; s >>= 1) { if (tid < s) red[tid] += red[tid + s]; __syncthreads(); }
  const float inv = 1.f / red[0];

  if (b == 0) {
    for (int k = tid; k < SEQ; k += 256) aw_out[k] = expf(sc[k] - M) * inv;
  }

  float a0 = 0.f, a1 = 0.f, a2 = 0.f, a3 = 0.f;
  for (int k = b * 16; k < b * 16 + 16; ++k) {
    float w = expf(sc[k] - M) * inv;
    float4 e = ((const float4*)(enc + (size_t)k * H))[tid];
    a0 += w * e.x;
    a1 += w * e.y;
    a2 += w * e.z;
    a3 += w * e.w;
  }
  atomicAdd(&ctx[tid * 4 + 0], a0);
  atomicAdd(&ctx[tid * 4 + 1], a1);
  atomicAdd(&ctx[tid * 4 + 2], a2);
  atomicAdd(&ctx[tid * 4 + 3], a3);
}

// ---------------- logits[row] = W_out[row] . [h1; ctx] + b_out[row]
// Unshifted sum of exp(logit) accumulated directly (one atomicAdd per block):
// logits here are provably small (|logit| <~ 6 for this weight scale), so
// exp without max-shift cannot overflow fp32, and log-softmax is shift-invariant.
// Block 0 also emits ctx -> out_ctx from its LDS staging copy.
__global__ __launch_bounds__(256) void k_logits(
    const float* __restrict__ h1, const float* __restrict__ ctx,
    const float* __restrict__ W_out, const float* __restrict__ b_out,
    float* __restrict__ logits, float* __restrict__ expsum,
    float* __restrict__ ctx_out)
{
  __shared__ float xs[2 * H];
  __shared__ float wexp[4];
  const int tid = threadIdx.x;
  for (int i = tid; i < H; i += 256) {
    xs[i]     = h1[i];
    xs[H + i] = ctx[i];
  }
  __syncthreads();
  if (blockIdx.x == 0) {
    for (int i = tid; i < H; i += 256) ctx_out[i] = xs[H + i];
  }
  const int wave = tid >> 6, lane = tid & 63;
  const int row = blockIdx.x * 4 + wave;
  float e = 0.f;                            // OOB rows contribute nothing
  if (row < V) {
    const float4* Wr = (const float4*)(W_out + (size_t)row * (2 * H));
    float a = 0.f;
#pragma unroll
    for (int c = 0; c < 8; ++c)
      a += dot4(Wr[c * 64 + lane], &xs[c * 256 + lane * 4]);
    a = wred(a);
    if (lane == 0) {
      float val = a + b_out[row];
      logits[row] = val;
      e = expf(val);
    }
  }
  if (lane == 0) wexp[wave] = e;
  __syncthreads();
  if (tid == 0)
    atomicAdd(expsum, wexp[0] + wexp[1] + wexp[2] + wexp[3]);
}

// ---------------- out[i] = logits[i] - log(sum_exp)
__global__ __launch_bounds__(256) void k_out(
    const float* __restrict__ logits, const float* __restrict__ expsum,
    float* __restrict__ out)
{
  const int i = blockIdx.x * 256 + threadIdx.x;
  const float lse = logf(*expsum);
  if (i < V) out[i] = logits[i] - lse;
}

} // anonymous namespace

extern "C" void kernel_launch(void* const* d_in, const int* in_sizes, int n_in,
                              void* d_out, int out_size, void* d_ws, size_t ws_size,
                              hipStream_t stream)
{
  const int*   word          = (const int*)d_in[0];
  const float* last_context  = (const float*)d_in[1];
  const float* last_hidden   = (const float*)d_in[2];   // (2,1,H)
  const float* enc           = (const float*)d_in[3];   // (S,1,H)
  const float* emb           = (const float*)d_in[4];   // (V,H)
  const float* W_ih0         = (const float*)d_in[5];
  const float* W_hh0         = (const float*)d_in[6];
  const float* b_ih0         = (const float*)d_in[7];
  const float* b_hh0         = (const float*)d_in[8];
  const float* W_ih1         = (const float*)d_in[9];
  const float* W_hh1         = (const float*)d_in[10];
  const float* b_ih1         = (const float*)d_in[11];
  const float* b_hh1         = (const float*)d_in[12];
  const float* Wa            = (const float*)d_in[13];
  // d_in[14] = ba — provably unused: softmax is shift-invariant and ba contributes
  // only the constant (ba . h1) to every score.
  const float* W_out         = (const float*)d_in[15];
  const float* b_out         = (const float*)d_in[16];

  float* ws = (float*)d_ws;
  float*    v      = ws;                       // [0, 1024)   — zeroed
  float*    ctx    = ws + 1024;                // [1024,2048) — zeroed
  float*    expsum = ws + 2048;                // 1 float     — zeroed
  float*    h0     = ws + 2560;                // 1024
  float*    h1     = ws + 3584;                // 1024
  float*    sc     = ws + 4608;                // 2048
  float*    logits = ws + 8704;                // V

  float* out     = (float*)d_out;
  float* out_ctx = out + V;
  float* out_h0  = out + V + H;
  float* out_h1  = out + V + 2 * H;
  float* out_att = out + V + 3 * H;

  hipMemsetAsync(d_ws, 0, 2052 * sizeof(float), stream);

  hipLaunchKernelGGL(k_gru0, dim3(256), dim3(256), 0, stream,
                     word, emb, last_context, last_hidden,
                     W_ih0, W_hh0, b_ih0, b_hh0, h0, out_h0);
  hipLaunchKernelGGL(k_gru1, dim3(256), dim3(256), 0, stream,
                     h0, last_hidden + H, W_ih1, W_hh1, b_ih1, b_hh1, h1, out_h1);
  hipLaunchKernelGGL(k_wat, dim3(64), dim3(256), 0, stream, Wa, h1, v);
  hipLaunchKernelGGL(k_scores, dim3(SEQ / 4), dim3(256), 0, stream, enc, v, sc);
  hipLaunchKernelGGL(k_ctx, dim3(SEQ / 16), dim3(256), 0, stream, enc, sc, ctx, out_att);
  hipLaunchKernelGGL(k_logits, dim3((V + 3) / 4), dim3(256), 0, stream,
                     h1, ctx, W_out, b_out, logits, expsum, out_ctx);
  hipLaunchKernelGGL(k_out, dim3((V + 255) / 256), dim3(256), 0, stream,
                     logits, expsum, out);
}

// Round 4
// 774.246 us; speedup vs baseline: 1.0122x; 1.0122x over previous
//
#include <hip/hip_runtime.h>

namespace {

constexpr int V   = 50257;
constexpr int H   = 1024;
constexpr int SEQ = 2048;

__device__ __forceinline__ float dot4(const float4 p, const float* __restrict__ x) {
  return p.x * x[0] + p.y * x[1] + p.z * x[2] + p.w * x[3];
}

__device__ __forceinline__ float wred(float v) {
#pragma unroll
  for (int off = 32; off; off >>= 1) v += __shfl_xor(v, off, 64);
  return v;
}

// Monotonic order-preserving float->uint encoding (all finite values map to key > 0,
// so a memset-0 sentinel behaves as -inf for atomicMax).
__device__ __forceinline__ unsigned fenc(float x) {
  unsigned u = __float_as_uint(x);
  return u ^ ((unsigned)((int)u >> 31) | 0x80000000u);
}
__device__ __forceinline__ float fdec(unsigned k) {
  unsigned u = k ^ (((int)k >= 0) ? 0xFFFFFFFFu : 0x80000000u);
  return __uint_as_float(u);
}

// ---------------- GRU layer 0: x = [emb[word]; last_context] (2048), h = last_hidden[0]
__global__ __launch_bounds__(256) void k_gru0(
    const int* __restrict__ word, const float* __restrict__ emb,
    const float* __restrict__ last_context, const float* __restrict__ last_hidden0,
    const float* __restrict__ W_ih, const float* __restrict__ W_hh,
    const float* __restrict__ b_ih, const float* __restrict__ b_hh,
    float* __restrict__ h_ws, float* __restrict__ h_out)
{
  __shared__ float xs[2 * H];
  __shared__ float hs[H];
  const int tid = threadIdx.x;
  const size_t wrow = (size_t)word[0] * H;
  for (int i = tid; i < H; i += 256) {
    xs[i]     = emb[wrow + i];
    xs[H + i] = last_context[i];
    hs[i]     = last_hidden0[i];
  }
  __syncthreads();
  const int wave = tid >> 6, lane = tid & 63;
  const int j = blockIdx.x * 4 + wave;   // gate row index, 0..1023
  float acc[6];
#pragma unroll
  for (int g = 0; g < 3; ++g) {
    const float4* Wr = (const float4*)(W_ih + (size_t)(g * H + j) * (2 * H));
    float a = 0.f;
#pragma unroll
    for (int c = 0; c < 8; ++c)
      a += dot4(Wr[c * 64 + lane], &xs[c * 256 + lane * 4]);
    acc[g] = a;
  }
#pragma unroll
  for (int g = 0; g < 3; ++g) {
    const float4* Wr = (const float4*)(W_hh + (size_t)(g * H + j) * H);
    float a = 0.f;
#pragma unroll
    for (int c = 0; c < 4; ++c)
      a += dot4(Wr[c * 64 + lane], &hs[c * 256 + lane * 4]);
    acc[3 + g] = a;
  }
#pragma unroll
  for (int g = 0; g < 6; ++g) acc[g] = wred(acc[g]);
  if (lane == 0) {
    float gir = acc[0] + b_ih[j];
    float giz = acc[1] + b_ih[H + j];
    float gin = acc[2] + b_ih[2 * H + j];
    float ghr = acc[3] + b_hh[j];
    float ghz = acc[4] + b_hh[H + j];
    float ghn = acc[5] + b_hh[2 * H + j];
    float r = 1.f / (1.f + expf(-(gir + ghr)));
    float z = 1.f / (1.f + expf(-(giz + ghz)));
    float n = tanhf(gin + r * ghn);
    float h = (1.f - z) * n + z * hs[j];
    h_ws[j]  = h;
    h_out[j] = h;
  }
}

// ---------------- GRU layer 1: x = h0 (fp32, 1024), h = last_hidden[1]
__global__ __launch_bounds__(256) void k_gru1(
    const float* __restrict__ x_ws, const float* __restrict__ last_hidden1,
    const float* __restrict__ W_ih, const float* __restrict__ W_hh,
    const float* __restrict__ b_ih, const float* __restrict__ b_hh,
    float* __restrict__ h_ws, float* __restrict__ h_out)
{
  __shared__ float xs[H];
  __shared__ float hs[H];
  const int tid = threadIdx.x;
  for (int i = tid; i < H; i += 256) {
    xs[i] = x_ws[i];
    hs[i] = last_hidden1[i];
  }
  __syncthreads();
  const int wave = tid >> 6, lane = tid & 63;
  const int j = blockIdx.x * 4 + wave;
  float acc[6];
#pragma unroll
  for (int g = 0; g < 3; ++g) {
    const float4* Wr = (const float4*)(W_ih + (size_t)(g * H + j) * H);
    float a = 0.f;
#pragma unroll
    for (int c = 0; c < 4; ++c)
      a += dot4(Wr[c * 64 + lane], &xs[c * 256 + lane * 4]);
    acc[g] = a;
  }
#pragma unroll
  for (int g = 0; g < 3; ++g) {
    const float4* Wr = (const float4*)(W_hh + (size_t)(g * H + j) * H);
    float a = 0.f;
#pragma unroll
    for (int c = 0; c < 4; ++c)
      a += dot4(Wr[c * 64 + lane], &hs[c * 256 + lane * 4]);
    acc[3 + g] = a;
  }
#pragma unroll
  for (int g = 0; g < 6; ++g) acc[g] = wred(acc[g]);
  if (lane == 0) {
    float gir = acc[0] + b_ih[j];
    float giz = acc[1] + b_ih[H + j];
    float gin = acc[2] + b_ih[2 * H + j];
    float ghr = acc[3] + b_hh[j];
    float ghz = acc[4] + b_hh[H + j];
    float ghn = acc[5] + b_hh[2 * H + j];
    float r = 1.f / (1.f + expf(-(gir + ghr)));
    float z = 1.f / (1.f + expf(-(giz + ghz)));
    float n = tanhf(gin + r * ghn);
    float h = (1.f - z) * n + z * hs[j];
    h_ws[j]  = h;
    h_out[j] = h;
  }
}

// ---------------- v = Wa^T @ h1   (ba dropped: softmax shift-invariant)
__global__ __launch_bounds__(256) void k_wat(
    const float* __restrict__ Wa, const float* __restrict__ h1, float* __restrict__ v)
{
  const int t = threadIdx.x, b = blockIdx.x;
  float a0 = 0.f, a1 = 0.f, a2 = 0.f, a3 = 0.f;
  for (int j = b * 16; j < b * 16 + 16; ++j) {
    float hj = h1[j];
    float4 w = ((const float4*)(Wa + (size_t)j * H))[t];
    a0 += hj * w.x;
    a1 += hj * w.y;
    a2 += hj * w.z;
    a3 += hj * w.w;
  }
  atomicAdd(&v[t * 4 + 0], a0);
  atomicAdd(&v[t * 4 + 1], a1);
  atomicAdd(&v[t * 4 + 2], a2);
  atomicAdd(&v[t * 4 + 3], a3);
}

// ---------------- scores[i] = enc[i] . v   (grid 512, wave per i)
__global__ __launch_bounds__(256) void k_scores(
    const float* __restrict__ enc, const float* __restrict__ v, float* __restrict__ sc)
{
  __shared__ float vs[H];
  const int tid = threadIdx.x;
  for (int i = tid; i < H; i += 256) vs[i] = v[i];
  __syncthreads();
  const int wave = tid >> 6, lane = tid & 63;
  const int i = blockIdx.x * 4 + wave;
  const float4* er = (const float4*)(enc + (size_t)i * H);
  float a = 0.f;
#pragma unroll
  for (int c = 0; c < 4; ++c)
    a += dot4(er[c * 64 + lane], &vs[c * 256 + lane * 4]);
  a = wred(a);
  if (lane == 0) sc[i] = a;
}

// ---------------- fused softmax + ctx (grid 128): each block redundantly
// reduces the 2048 scores (8 KB, L2-resident) then accumulates its i-slab.
// Block 0 additionally writes the normalized weights to out_att.
__global__ __launch_bounds__(256) void k_ctx(
    const float* __restrict__ enc, const float* __restrict__ sc,
    float* __restrict__ ctx, float* __restrict__ aw_out)
{
  __shared__ float red[256];
  const int tid = threadIdx.x, b = blockIdx.x;
  float m = -1e30f;
  for (int k = tid; k < SEQ; k += 256) m = fmaxf(m, sc[k]);
  red[tid] = m; __syncthreads();
  for (int s = 128; s; s >>= 1) { if (tid < s) red[tid] = fmaxf(red[tid], red[tid + s]); __syncthreads(); }
  const float M = red[0]; __syncthreads();
  float sum = 0.f;
  for (int k = tid; k < SEQ; k += 256) sum += expf(sc[k] - M);
  red[tid] = sum; __syncthreads();
  for (int s = 128; s; s >>= 1) { if (tid < s) red[tid] += red[tid + s]; __syncthreads(); }
  const float inv = 1.f / red[0];

  if (b == 0) {
    for (int k = tid; k < SEQ; k += 256) aw_out[k] = expf(sc[k] - M) * inv;
  }

  float a0 = 0.f, a1 = 0.f, a2 = 0.f, a3 = 0.f;
  for (int k = b * 16; k < b * 16 + 16; ++k) {
    float w = expf(sc[k] - M) * inv;
    float4 e = ((const float4*)(enc + (size_t)k * H))[tid];
    a0 += w * e.x;
    a1 += w * e.y;
    a2 += w * e.z;
    a3 += w * e.w;
  }
  atomicAdd(&ctx[tid * 4 + 0], a0);
  atomicAdd(&ctx[tid * 4 + 1], a1);
  atomicAdd(&ctx[tid * 4 + 2], a2);
  atomicAdd(&ctx[tid * 4 + 3], a3);
}

// ---------------- logits[row] = W_out[row] . [h1; ctx] + b_out[row]
// Per-block max folded into one atomicMax (exact, order-independent);
// block 0 also emits ctx -> out_ctx from its LDS staging copy.
__global__ __launch_bounds__(256) void k_logits(
    const float* __restrict__ h1, const float* __restrict__ ctx,
    const float* __restrict__ W_out, const float* __restrict__ b_out,
    float* __restrict__ logits, unsigned* __restrict__ maxkey,
    float* __restrict__ ctx_out)
{
  __shared__ float xs[2 * H];
  __shared__ float wmax[4];
  const int tid = threadIdx.x;
  for (int i = tid; i < H; i += 256) {
    xs[i]     = h1[i];
    xs[H + i] = ctx[i];
  }
  __syncthreads();
  if (blockIdx.x == 0) {
    for (int i = tid; i < H; i += 256) ctx_out[i] = xs[H + i];
  }
  const int wave = tid >> 6, lane = tid & 63;
  const int row = blockIdx.x * 4 + wave;
  float val = -3.0e38f;                       // finite sentinel for OOB rows
  if (row < V) {
    const float4* Wr = (const float4*)(W_out + (size_t)row * (2 * H));
    float a = 0.f;
#pragma unroll
    for (int c = 0; c < 8; ++c)
      a += dot4(Wr[c * 64 + lane], &xs[c * 256 + lane * 4]);
    a = wred(a);
    if (lane == 0) {
      val = a + b_out[row];
      logits[row] = val;
    }
  }
  if (lane == 0) wmax[wave] = val;
  __syncthreads();
  if (tid == 0) {
    float m = fmaxf(fmaxf(wmax[0], wmax[1]), fmaxf(wmax[2], wmax[3]));
    atomicMax(maxkey, fenc(m));              // maxkey zeroed => acts as -inf
  }
}

// ---------------- partial sum of exp(logits - M), atomically merged (grid 64)
__global__ __launch_bounds__(256) void k_lse_sum(
    const float* __restrict__ logits, const unsigned* __restrict__ maxkey,
    float* __restrict__ expsum)
{
  __shared__ float red[256];
  const int tid = threadIdx.x;
  const float M = fdec(*maxkey);
  float s = 0.f;
  for (int i = blockIdx.x * 256 + tid; i < V; i += 64 * 256)
    s += expf(logits[i] - M);
  red[tid] = s; __syncthreads();
  for (int st = 128; st; st >>= 1) { if (tid < st) red[tid] += red[tid + st]; __syncthreads(); }
  if (tid == 0) atomicAdd(expsum, red[0]);
}

// ---------------- out[i] = logits[i] - (M + log(sum))
__global__ __launch_bounds__(256) void k_out(
    const float* __restrict__ logits, const unsigned* __restrict__ maxkey,
    const float* __restrict__ expsum, float* __restrict__ out)
{
  const int i = blockIdx.x * 256 + threadIdx.x;
  const float lse = fdec(*maxkey) + logf(*expsum);
  if (i < V) out[i] = logits[i] - lse;
}

} // anonymous namespace

extern "C" void kernel_launch(void* const* d_in, const int* in_sizes, int n_in,
                              void* d_out, int out_size, void* d_ws, size_t ws_size,
                              hipStream_t stream)
{
  const int*   word          = (const int*)d_in[0];
  const float* last_context  = (const float*)d_in[1];
  const float* last_hidden   = (const float*)d_in[2];   // (2,1,H)
  const float* enc           = (const float*)d_in[3];   // (S,1,H)
  const float* emb           = (const float*)d_in[4];   // (V,H)
  const float* W_ih0         = (const float*)d_in[5];
  const float* W_hh0         = (const float*)d_in[6];
  const float* b_ih0         = (const float*)d_in[7];
  const float* b_hh0         = (const float*)d_in[8];
  const float* W_ih1         = (const float*)d_in[9];
  const float* W_hh1         = (const float*)d_in[10];
  const float* b_ih1         = (const float*)d_in[11];
  const float* b_hh1         = (const float*)d_in[12];
  const float* Wa            = (const float*)d_in[13];
  // d_in[14] = ba — provably unused: softmax is shift-invariant and ba contributes
  // only the constant (ba . h1) to every score.
  const float* W_out         = (const float*)d_in[15];
  const float* b_out         = (const float*)d_in[16];

  float* ws = (float*)d_ws;
  float*    v      = ws;                       // [0, 1024)   — zeroed
  float*    ctx    = ws + 1024;                // [1024,2048) — zeroed
  unsigned* maxkey = (unsigned*)(ws + 2048);   // 1 uint     — zeroed (= -inf key)
  float*    expsum = ws + 2049;                // 1 float    — zeroed
  float*    h0     = ws + 2560;                // 1024
  float*    h1     = ws + 3584;                // 1024
  float*    sc     = ws + 4608;                // 2048
  float*    logits = ws + 8704;                // V

  float* out     = (float*)d_out;
  float* out_ctx = out + V;
  float* out_h0  = out + V + H;
  float* out_h1  = out + V + 2 * H;
  float* out_att = out + V + 3 * H;

  hipMemsetAsync(d_ws, 0, 2304 * sizeof(float), stream);

  hipLaunchKernelGGL(k_gru0, dim3(256), dim3(256), 0, stream,
                     word, emb, last_context, last_hidden,
                     W_ih0, W_hh0, b_ih0, b_hh0, h0, out_h0);
  hipLaunchKernelGGL(k_gru1, dim3(256), dim3(256), 0, stream,
                     h0, last_hidden + H, W_ih1, W_hh1, b_ih1, b_hh1, h1, out_h1);
  hipLaunchKernelGGL(k_wat, dim3(64), dim3(256), 0, stream, Wa, h1, v);
  hipLaunchKernelGGL(k_scores, dim3(SEQ / 4), dim3(256), 0, stream, enc, v, sc);
  hipLaunchKernelGGL(k_ctx, dim3(SEQ / 16), dim3(256), 0, stream, enc, sc, ctx, out_att);
  hipLaunchKernelGGL(k_logits, dim3((V + 3) / 4), dim3(256), 0, stream,
                     h1, ctx, W_out, b_out, logits, maxkey, out_ctx);
  hipLaunchKernelGGL(k_lse_sum, dim3(64), dim3(256), 0, stream,
                     logits, maxkey, expsum);
  hipLaunchKernelGGL(k_out, dim3((V + 255) / 256), dim3(256), 0, stream,
                     logits, maxkey, expsum, out);
}